// Round 13
// baseline (81.522 us; speedup 1.0000x reference)
//
#include <hip/hip_runtime.h>
#include <hip/hip_bf16.h>
#include <math.h>

#define B_ 64
#define T_ 512
#define D_ 768
#define H_ 96
#define M_ (B_*T_)   // 32768 rows

typedef __attribute__((ext_vector_type(8))) short short8;
typedef __attribute__((ext_vector_type(4))) float f32x4;

__device__ __forceinline__ short f2bf(float f) {
  unsigned u = __float_as_uint(f);
  unsigned r = (u + 0x7FFFu + ((u >> 16) & 1u)) >> 16;   // RTNE
  return (short)r;
}

__device__ __forceinline__ void gl16(const void* g, void* l) {
  __builtin_amdgcn_global_load_lds(
      (const __attribute__((address_space(1))) unsigned*)g,
      (__attribute__((address_space(3))) unsigned*)l, 16, 0, 0);
}

// ---------------------------------------------------------------------------
// Kernel 0: W -> bf16, transposed to [n][k] (n = mi*96+cc, 288 x 768).
// ---------------------------------------------------------------------------
__global__ __launch_bounds__(256) void wt_kernel(
    const float* __restrict__ Wq, const float* __restrict__ Wk,
    const float* __restrict__ Wv, short* __restrict__ wt)
{
  int id = blockIdx.x * 256 + threadIdx.x;     // 3*96*768 = 221184
  if (id >= 3*H_*D_) return;
  int n = id % 288;
  int k = id / 288;
  int mi = n / 96, cc = n % 96;
  const float* Wm = (mi == 0) ? Wq : ((mi == 1) ? Wk : Wv);
  wt[(size_t)n * D_ + k] = f2bf(Wm[(size_t)k * H_ + cc]);
}

// ---------------------------------------------------------------------------
// Kernel 1: QKV projection, global_load_lds GEMM (staging identical to R12).
// R12 post-mortem: staging structure is NOT the wall — rounds 6/8/12 (three
// different staging schemes) all pin at ~58 us; round 5 (same MFMA body,
// coalesced fp32 outputs) ran ~28 us.  Invariant since round 6: the v
// transposed SCATTER store (8 B/lane at 1 KB stride = 64 txns/wave-store).
// This round: v stored row-major bf16 like q/k (coalesced); attn does the
// transpose in LDS.  Epilogue is the ONLY change vs R12.
// ---------------------------------------------------------------------------
#define BKP 32

__global__ __launch_bounds__(256) void qkv_mfma_kernel(
    const float* __restrict__ x, const short* __restrict__ wt,
    short* __restrict__ qb, short* __restrict__ kb, short* __restrict__ vb)
{
  __shared__ float As[2][64][32];    // 16,384 B  (128 B/row = 8 x 16B slots)
  __shared__ short Bs[2][288][32];   // 36,864 B  ( 64 B/row = 4 x 16B slots)

  const int t    = threadIdx.x;
  const int row0 = blockIdx.x * 64;
  const int lane = t & 63;
  const int w    = t >> 6;        // 0..3: wave owns rows [row0+16w, +16)
  const int l15  = lane & 15;
  const int l4   = lane >> 4;

  // ---- staging: global_load_lds, 1 KB per wave-instr, linear LDS dest ----
  auto stageA = [&](int buf, int k0) {
    #pragma unroll
    for (int i = 0; i < 2; ++i) {
      int inst = w * 2 + i;                     // 0..7, 8 rows each
      int row  = inst * 8 + (lane >> 3);
      int c16  = (lane & 7) ^ ((lane >> 3) & 7);   // pre-swizzled source col
      const char* g = (const char*)(x + (size_t)(row0 + row) * D_ + k0) + c16 * 16;
      char* l = (char*)&As[buf][0][0] + inst * 1024 + lane * 16;
      gl16(g, l);
    }
  };
  auto stageB = [&](int buf, int k0) {
    #pragma unroll
    for (int i = 0; i < 5; ++i) {
      int inst = w + 4 * i;                     // 0..19, guard to 18
      if (inst < 18) {
        int row = inst * 16 + (lane >> 2);      // 0..287
        int c16 = (lane & 3) ^ ((lane >> 2) & 3);
        const char* g = (const char*)(wt + (size_t)row * D_ + k0) + c16 * 16;
        char* l = (char*)&Bs[buf][0][0] + inst * 1024 + lane * 16;
        gl16(g, l);
      }
    }
  };

  f32x4 acc[18];
  #pragma unroll
  for (int ci = 0; ci < 18; ++ci) acc[ci] = (f32x4){0.f, 0.f, 0.f, 0.f};

  stageA(0, 0);
  stageB(0, 0);
  __syncthreads();

  const int arow = w * 16 + l15;                // A row this lane reads
  const char* Abase = (const char*)&As[0][0][0];
  const char* Bbase = (const char*)&Bs[0][0][0];

  for (int ks = 0; ks < 24; ++ks) {
    int buf = ks & 1;
    if (ks + 1 < 24) { stageA(buf ^ 1, (ks + 1) * BKP); stageB(buf ^ 1, (ks + 1) * BKP); }

    // A-frag: fp32 swizzled read + convert (k = l4*8 .. +8)
    const char* ab = Abase + (size_t)buf * 8192 + arow * 128;
    float4 a0 = *reinterpret_cast<const float4*>(ab + (((l4 * 2 + 0) ^ (arow & 7)) * 16));
    float4 a1 = *reinterpret_cast<const float4*>(ab + (((l4 * 2 + 1) ^ (arow & 7)) * 16));
    short8 af;
    af[0] = f2bf(a0.x); af[1] = f2bf(a0.y); af[2] = f2bf(a0.z); af[3] = f2bf(a0.w);
    af[4] = f2bf(a1.x); af[5] = f2bf(a1.y); af[6] = f2bf(a1.z); af[7] = f2bf(a1.w);

    #pragma unroll
    for (int ci = 0; ci < 18; ++ci) {
      int brow = ci * 16 + l15;
      short8 bf = *reinterpret_cast<const short8*>(
          Bbase + (size_t)buf * 18432 + brow * 64 + ((l4 ^ (brow & 3)) * 16));
      acc[ci] = __builtin_amdgcn_mfma_f32_16x16x32_bf16(af, bf, acc[ci], 0, 0, 0);
    }
    __syncthreads();
  }

  // epilogue: acc[ci]: rows = row0 + w*16 + l4*4 + reg, col = ci*16 + l15.
  // ALL three outputs coalesced row-major bf16 [M][96] (v scatter removed).
  const int rbase = row0 + w * 16 + l4 * 4;
  #pragma unroll
  for (int ci = 0; ci < 18; ++ci) {
    int mi = ci / 6;
    int cc = (ci % 6) * 16 + l15;
    short* Om = (mi == 0) ? qb : ((mi == 1) ? kb : vb);
    #pragma unroll
    for (int reg = 0; reg < 4; ++reg)
      Om[(size_t)(rbase + reg) * H_ + cc] = f2bf(acc[ci][reg]);
  }
}

// ---------------------------------------------------------------------------
// Kernel 2: causal flash attention via MFMA bf16.  V now arrives row-major;
// transpose happens during LDS staging (coalesced loads + scalar ds_writes,
// tok-group XOR swizzle keyed on h>>3 to break the h-step-8 bank collapse).
// ---------------------------------------------------------------------------
#define QB 32
#define KVB 32
#define KSTR 104
#define VSTR 40
#define PSTR 40

__global__ __launch_bounds__(128) void attn_mfma_kernel(
    const short* __restrict__ qb, const short* __restrict__ kb,
    const short* __restrict__ vb, float* __restrict__ out)
{
  __shared__ short ks[KVB][KSTR];     // 6656 B
  __shared__ short vs[H_][VSTR];      // 7680 B
  __shared__ short ps[2][16][PSTR];   // 2560 B

  const int t    = threadIdx.x;
  const int lane = t & 63;
  const int w    = t >> 6;            // 0..1
  const int l15  = lane & 15;
  const int l4   = lane >> 4;
  const int qi   = 15 - blockIdx.x;   // heavy blocks first
  const int b    = blockIdx.y;
  const int q0   = qi * QB;

  short8 qf[3];
  {
    const short* qbase = qb + ((size_t)(b * T_) + q0 + w * 16 + l15) * H_;
    #pragma unroll
    for (int f = 0; f < 3; ++f)
      qf[f] = *reinterpret_cast<const short8*>(qbase + f * 32 + l4 * 8);
  }

  f32x4 acc[6];
  #pragma unroll
  for (int c = 0; c < 6; ++c) acc[c] = (f32x4){0.f, 0.f, 0.f, 0.f};
  float m_r[4] = {-INFINITY, -INFINITY, -INFINITY, -INFINITY};
  float l_r[4] = {0.f, 0.f, 0.f, 0.f};
  const float scale = 0.10206207261596576f;   // 1/sqrt(96)

  const int jmax = q0 + QB;
  for (int j0 = 0; j0 < jmax; j0 += KVB) {
    __syncthreads();
    {  // stage K tile: 32 rows x 96 bf16
      int row = t >> 2, seg = t & 3;
      const short* src = kb + ((size_t)(b * T_) + j0 + row) * H_ + seg * 24;
      short* dst = &ks[row][seg * 24];
      *reinterpret_cast<short8*>(dst)      = *reinterpret_cast<const short8*>(src);
      *reinterpret_cast<short8*>(dst + 8)  = *reinterpret_cast<const short8*>(src + 8);
      *reinterpret_cast<short8*>(dst + 16) = *reinterpret_cast<const short8*>(src + 16);
    }
    {  // stage V tile: transpose 32 tok x 96 h -> vs[h][tokS]
      #pragma unroll
      for (int i = 0; i < 3; ++i) {
        int c = t + i * 128;            // 0..383
        int tok = c / 12;               // 0..31
        int m   = c % 12;               // h-group (h0 = 8m)
        int h0  = m * 8;
        short8 v = *reinterpret_cast<const short8*>(
            vb + (size_t)(b * T_ + j0 + tok) * H_ + h0);
        int tokS = tok ^ ((m & 3) << 3);     // swizzled tok slot
        #pragma unroll
        for (int j = 0; j < 8; ++j) vs[h0 + j][tokS] = v[j];
      }
    }
    __syncthreads();

    f32x4 sfr[2];
    sfr[0] = (f32x4){0.f,0.f,0.f,0.f};
    sfr[1] = (f32x4){0.f,0.f,0.f,0.f};
    #pragma unroll
    for (int ct = 0; ct < 2; ++ct)
      #pragma unroll
      for (int f = 0; f < 3; ++f) {
        short8 kf = *reinterpret_cast<const short8*>(&ks[ct * 16 + l15][f * 32 + l4 * 8]);
        sfr[ct] = __builtin_amdgcn_mfma_f32_16x16x32_bf16(qf[f], kf, sfr[ct], 0, 0, 0);
      }

    const int qrow = q0 + w * 16 + l4 * 4;   // +reg
    float p0[4], p1[4], fsc[4];
    #pragma unroll
    for (int reg = 0; reg < 4; ++reg) {
      float s0 = sfr[0][reg] * scale;
      float s1 = sfr[1][reg] * scale;
      if (j0 + l15      > qrow + reg) s0 = -INFINITY;
      if (j0 + l15 + 16 > qrow + reg) s1 = -INFINITY;
      float tm = fmaxf(s0, s1);
      #pragma unroll
      for (int o = 1; o < 16; o <<= 1) tm = fmaxf(tm, __shfl_xor(tm, o));
      float Mnew = fmaxf(m_r[reg], tm);
      p0[reg] = __expf(s0 - Mnew);
      p1[reg] = __expf(s1 - Mnew);
      float psum = p0[reg] + p1[reg];
      #pragma unroll
      for (int o = 1; o < 16; o <<= 1) psum += __shfl_xor(psum, o);
      fsc[reg] = __expf(m_r[reg] - Mnew);
      m_r[reg] = Mnew;
      l_r[reg] = l_r[reg] * fsc[reg] + psum;
    }
    #pragma unroll
    for (int c = 0; c < 6; ++c)
      #pragma unroll
      for (int reg = 0; reg < 4; ++reg) acc[c][reg] *= fsc[reg];

    #pragma unroll
    for (int reg = 0; reg < 4; ++reg) {
      ps[w][l4 * 4 + reg][l15]      = f2bf(p0[reg]);
      ps[w][l4 * 4 + reg][l15 + 16] = f2bf(p1[reg]);
    }
    short8 pa = *reinterpret_cast<const short8*>(&ps[w][l15][l4 * 8]);

    #pragma unroll
    for (int c = 0; c < 6; ++c) {
      int h = c * 16 + l15;
      short8 vf = *reinterpret_cast<const short8*>(
          &vs[h][(l4 ^ ((h >> 3) & 3)) * 8]);   // un-swizzle tok group
      acc[c] = __builtin_amdgcn_mfma_f32_16x16x32_bf16(pa, vf, acc[c], 0, 0, 0);
    }
  }

  float inv[4];
  #pragma unroll
  for (int reg = 0; reg < 4; ++reg) inv[reg] = 1.f / l_r[reg];
  #pragma unroll
  for (int c = 0; c < 6; ++c) {
    #pragma unroll
    for (int reg = 0; reg < 4; ++reg) {
      size_t row = (size_t)(b * T_) + q0 + w * 16 + l4 * 4 + reg;
      out[row * H_ + c * 16 + l15] = acc[c][reg] * inv[reg];
    }
  }
}

extern "C" void kernel_launch(void* const* d_in, const int* in_sizes, int n_in,
                              void* d_out, int out_size, void* d_ws, size_t ws_size,
                              hipStream_t stream) {
  const float* x  = (const float*)d_in[0];
  const float* Wq = (const float*)d_in[1];
  const float* Wk = (const float*)d_in[2];
  const float* Wv = (const float*)d_in[3];

  short* wt = (short*)d_ws;                                // 442,368 B
  short* qb = (short*)((char*)d_ws + 524288);              // 6,291,456 B
  short* kb = qb + (size_t)M_ * H_;
  short* vb = kb + (size_t)M_ * H_;                        // row-major [M][96]
  float* outp = (float*)d_out;

  hipLaunchKernelGGL(wt_kernel, dim3((3*H_*D_ + 255)/256), dim3(256), 0, stream,
                     Wq, Wk, Wv, wt);
  hipLaunchKernelGGL(qkv_mfma_kernel, dim3(M_/64), dim3(256), 0, stream,
                     x, wt, qb, kb, vb);
  hipLaunchKernelGGL(attn_mfma_kernel, dim3(T_/QB, B_), dim3(128), 0, stream,
                     qb, kb, vb, outp);
}